// Round 5
// baseline (38.291 us; speedup 1.0000x reference)
//
#include <hip/hip_runtime.h>
#include <hip/hip_bf16.h>

#define B_ROWS 32768
#define D_IN   128
#define H1_    256
#define HTAU   32
#define NBLK   128

#define NE     64
#define SMIN  (-8.0f)
#define SMAX  ( 8.0f)

typedef __bf16 bf16_t;
typedef bf16_t bf16x8 __attribute__((ext_vector_type(8)));
typedef float  f32x4  __attribute__((ext_vector_type(4)));

__device__ __forceinline__ bf16x8 cvt8(const float* v) {
    bf16x8 r;
#pragma unroll
    for (int i = 0; i < 8; ++i) r[i] = (bf16_t)v[i];
    return r;
}

// async global->LDS, 16B/lane; LDS dest = wave-uniform base + lane*16
__device__ __forceinline__ void gload_lds16(const void* g, void* l) {
    __builtin_amdgcn_global_load_lds(
        (const __attribute__((address_space(1))) uint32_t*)g,
        (__attribute__((address_space(3))) uint32_t*)l, 16, 0, 0);
}

// ---------------------------------------------------------------------------
// prep: blocks [0,32):  tau table pairs tab2[n][e] = (f_n(s_e), f_n(s_{e+1}))
//                       n = bid*4+(tid>>6), e = tid&63, NE=64 over [-8,8]
//       blocks [32,80): W1,W2 -> bf16 in MFMA fragment order
// fragment order (k-step kk, chunk c in [0,1024)): nf=c>>6, ll=c&63,
//   col = nf*16 + (ll&15), k = kk*32 + (ll>>4)*8 + i   (i = 0..7)
// ---------------------------------------------------------------------------
__global__ void prep(const float* __restrict__ w1, const float* __restrict__ w2,
                     const float* __restrict__ wt1, const float* __restrict__ bt1,
                     const float* __restrict__ wt2, const float* __restrict__ bt2,
                     float2* __restrict__ tab2,
                     bf16x8* __restrict__ w1f, bf16x8* __restrict__ w2f) {
    const int bid = blockIdx.x, tid = threadIdx.x;
    if (bid < 32) {
        const int n = bid * 4 + (tid >> 6);
        const int e = tid & 63;
        float s = SMIN + (SMAX - SMIN) * (float)e / (float)(NE - 1);
        float acc = bt2[n];
        for (int h = 0; h < HTAU; ++h) {
            float z  = s * wt1[n * HTAU + h] + bt1[n * HTAU + h];
            float sp = (z > 20.f) ? z : log1pf(expf(z));
            acc += wt2[n * HTAU + h] * sp;
        }
        float nxt = __shfl_down(acc, 1, 64);          // e==63 never interpolated
        tab2[n * NE + e] = make_float2(acc, nxt);
    } else {
        const int cid  = (bid - 32) * 256 + tid;      // 0..12287
        const int isW2 = cid >= 4096;
        const int c2   = isW2 ? cid - 4096 : cid;
        const int kk = c2 >> 10, c = c2 & 1023;
        const int nf = c >> 6,  ll = c & 63;
        const int col = nf * 16 + (ll & 15);
        const int kr  = kk * 32 + (ll >> 4) * 8;
        const float* src = isW2 ? (w2 + col * H1_ + kr) : (w1 + col * D_IN + kr);
        float tmp[8];
        *(f32x4*)tmp       = *(const f32x4*)src;
        *(f32x4*)(tmp + 4) = *(const f32x4*)(src + 4);
        (isW2 ? w2f : w1f)[c2] = cvt8(tmp);
    }
}

// ---------------------------------------------------------------------------
// fused_main: mu branch (MFMA) + tau/out_lr branch, one pass over x.
// BM=64 rows/wg, 256 threads (4 waves), grid 512, 2 wgs/CU.
// T3 minimal 2-phase: double-buffered W stage; per k-step:
//   STAGE(next slice) -> MFMA(cur slice) -> __syncthreads()
// so stage latency flies under the MFMA cluster. 12 barriers (was 24).
// LDS = 32KB wsl dbuf + 32KB h1 (swizzled bf16) = 64.5KB -> 2 wgs/CU.
// ---------------------------------------------------------------------------
__global__ __launch_bounds__(256, 2)
void fused_main(const float* __restrict__ x,
                const bf16x8* __restrict__ w1f, const bf16x8* __restrict__ w2f,
                const float* __restrict__ b1, const float* __restrict__ b2,
                const float* __restrict__ w3, const float* __restrict__ b3,
                const float2* __restrict__ tab2, const float* __restrict__ wlr,
                const float* __restrict__ blr,
                float* __restrict__ mu_out, float* __restrict__ lr_out) {
    __shared__ bf16x8 wsl[2][1024];      // 2 x 16KB staged W k-slice (frag order)
    __shared__ char   h1_raw[64 * 512];  // 32KB bf16 [64][256], swizzled

    const int tid = threadIdx.x;
    const int l   = tid & 63;
    const int w   = tid >> 6;            // wave 0..3
    const int q   = l >> 4;
    const int l15 = l & 15;
    const int row = w * 16 + l15;        // block-local row 0..63
    const int rb  = blockIdx.x * 64;

    // ---- prologue: stage W1 k-step 0 into buf 0; x row + w_lr to regs ----
#pragma unroll
    for (int j = 0; j < 4; ++j)
        gload_lds16(w1f + w * 256 + j * 64 + l, &wsl[0][w * 256 + j * 64]);

    float xv[32], wlv[32];
    {
        const float* xr = x + (size_t)(rb + row) * D_IN;
#pragma unroll
        for (int kk = 0; kk < 4; ++kk) {
            *(f32x4*)(xv + kk * 8)      = *(const f32x4*)(xr + kk * 32 + q * 8);
            *(f32x4*)(xv + kk * 8 + 4)  = *(const f32x4*)(xr + kk * 32 + q * 8 + 4);
            *(f32x4*)(wlv + kk * 8)     = *(const f32x4*)(wlr + kk * 32 + q * 8);
            *(f32x4*)(wlv + kk * 8 + 4) = *(const f32x4*)(wlr + kk * 32 + q * 8 + 4);
        }
    }
    bf16x8 a1[4];
#pragma unroll
    for (int kk = 0; kk < 4; ++kk) a1[kk] = cvt8(xv + kk * 8);

    // ---- tau branch (L2 gathers overlap the W1 staging drain) ----
    {
        const float INVDS = (float)(NE - 1) / (SMAX - SMIN);
        float tsum = 0.f;
#pragma unroll
        for (int kk = 0; kk < 4; ++kk) {
#pragma unroll
            for (int i = 0; i < 8; ++i) {
                float s = xv[kk * 8 + i];
                s = fminf(fmaxf(s, SMIN), SMAX);
                float u = (s - SMIN) * INVDS;
                int ii = (int)u;
                ii = ii > NE - 2 ? NE - 2 : ii;
                float fr = u - (float)ii;
                int n = kk * 32 + q * 8 + i;
                float2 tv = tab2[n * NE + ii];
                tsum += wlv[kk * 8 + i] * (tv.x + (tv.y - tv.x) * fr);
            }
        }
        tsum += __shfl_xor(tsum, 16, 64);
        tsum += __shfl_xor(tsum, 32, 64);
        if (q == 0) lr_out[rb + row] = tsum + blr[0];
    }

    f32x4 acc[16];
#pragma unroll
    for (int f = 0; f < 16; ++f) acc[f] = (f32x4){0.f, 0.f, 0.f, 0.f};

    __syncthreads();                      // buf0 (W1 k0) resident

    // ---- mu layer 1 (K = 128, 4 k-steps; cur = kk&1) ----
#pragma unroll
    for (int kk = 0; kk < 4; ++kk) {
        const int cur = kk & 1;
        const bf16x8* nsrc = (kk < 3) ? (w1f + (kk + 1) * 1024) : w2f;
#pragma unroll
        for (int j = 0; j < 4; ++j)       // stage NEXT slice into other buf
            gload_lds16(nsrc + w * 256 + j * 64 + l, &wsl[cur ^ 1][w * 256 + j * 64]);
#pragma unroll
        for (int nf = 0; nf < 16; ++nf)
            acc[nf] = __builtin_amdgcn_mfma_f32_16x16x32_bf16(a1[kk], wsl[cur][nf * 64 + l], acc[nf], 0, 0, 0);

        if (kk == 3) {  // epilogue 1: h1 = relu(acc+b1) -> LDS (wave-private rows)
#pragma unroll
            for (int f = 0; f < 16; ++f) {
                int col = f * 16 + l15;
                float bias = b1[col];
#pragma unroll
                for (int r = 0; r < 4; ++r) {
                    int gr = w * 16 + q * 4 + r;
                    float v = acc[f][r] + bias;
                    v = v > 0.f ? v : 0.f;
                    int byte = (gr * 512 + col * 2) ^ ((gr & 7) << 4);
                    *(bf16_t*)(h1_raw + byte) = (bf16_t)v;
                }
                acc[f] = (f32x4){0.f, 0.f, 0.f, 0.f};
            }
        }
        __syncthreads();                  // next slice resident; cur free
    }

    // ---- mu layer 2 (K = 256, 8 k-steps; cur = kk&1) ----
#pragma unroll
    for (int kk = 0; kk < 8; ++kk) {
        const int cur = kk & 1;
        if (kk < 7) {
#pragma unroll
            for (int j = 0; j < 4; ++j)
                gload_lds16(w2f + (kk + 1) * 1024 + w * 256 + j * 64 + l,
                            &wsl[cur ^ 1][w * 256 + j * 64]);
        }
        int k0   = kk * 32 + q * 8;
        int byte = (row * 512 + k0 * 2) ^ ((row & 7) << 4);
        bf16x8 a = *(bf16x8*)(h1_raw + byte);
#pragma unroll
        for (int nf = 0; nf < 16; ++nf)
            acc[nf] = __builtin_amdgcn_mfma_f32_16x16x32_bf16(a, wsl[cur][nf * 64 + l], acc[nf], 0, 0, 0);
        if (kk < 7) __syncthreads();
    }

    // ---- epilogue 2: mu = relu(acc + b2) . w3 + b3 ----
    float p[4] = {0.f, 0.f, 0.f, 0.f};
#pragma unroll
    for (int f = 0; f < 16; ++f) {
        int col = f * 16 + l15;
        float bias = b2[col];
        float wv   = w3[col];
#pragma unroll
        for (int r = 0; r < 4; ++r) {
            float v = acc[f][r] + bias;
            v = v > 0.f ? v : 0.f;
            p[r] += v * wv;
        }
    }
#pragma unroll
    for (int m = 1; m < 16; m <<= 1) {
#pragma unroll
        for (int r = 0; r < 4; ++r) p[r] += __shfl_xor(p[r], m, 64);
    }
    if (l15 == 0) {
        float bb = b3[0];
#pragma unroll
        for (int r = 0; r < 4; ++r)
            mu_out[rb + w * 16 + q * 4 + r] = p[r] + bb;
    }
}

extern "C" void kernel_launch(void* const* d_in, const int* in_sizes, int n_in,
                              void* d_out, int out_size, void* d_ws, size_t ws_size,
                              hipStream_t stream) {
    const float* x   = (const float*)d_in[0];
    const float* w1  = (const float*)d_in[1];
    const float* b1  = (const float*)d_in[2];
    const float* w2  = (const float*)d_in[3];
    const float* b2  = (const float*)d_in[4];
    const float* w3  = (const float*)d_in[5];
    const float* b3  = (const float*)d_in[6];
    const float* wt1 = (const float*)d_in[7];
    const float* bt1 = (const float*)d_in[8];
    const float* wt2 = (const float*)d_in[9];
    const float* bt2 = (const float*)d_in[10];
    const float* wlr = (const float*)d_in[11];
    const float* blr = (const float*)d_in[12];

    float* out    = (float*)d_out;
    float* mu_out = out;                 // output 0: mu     [32768]
    float* lr_out = out + B_ROWS;        // output 1: out_lr [32768]

    char* ws = (char*)d_ws;
    float2* tab2 = (float2*)ws;                   // 64KB  (128*64 float2)
    bf16x8* w1f  = (bf16x8*)(ws + (64 << 10));    // 64KB  (4096 chunks)
    bf16x8* w2f  = (bf16x8*)(ws + (128 << 10));   // 128KB (8192 chunks)

    prep<<<80, 256, 0, stream>>>(w1, w2, wt1, bt1, wt2, bt2, tab2, w1f, w2f);
    fused_main<<<B_ROWS / 64, 256, 0, stream>>>(x, w1f, w2f, b1, b2, w3, b3,
                                                tab2, wlr, blr, mu_out, lr_out);
}

// Round 6
// 34.331 us; speedup vs baseline: 1.1154x; 1.1154x over previous
//
#include <hip/hip_runtime.h>
#include <hip/hip_bf16.h>

#define B_ROWS 32768
#define D_IN   128
#define H1_    256
#define HTAU   32
#define NBLK   128

#define NE     64
#define SMIN  (-8.0f)
#define SMAX  ( 8.0f)

typedef __bf16 bf16_t;
typedef bf16_t bf16x8 __attribute__((ext_vector_type(8)));
typedef float  f32x4  __attribute__((ext_vector_type(4)));

__device__ __forceinline__ bf16x8 cvt8(const float* v) {
    bf16x8 r;
#pragma unroll
    for (int i = 0; i < 8; ++i) r[i] = (bf16_t)v[i];
    return r;
}

// async global->LDS, 16B/lane; LDS dest = wave-uniform base + lane*16
__device__ __forceinline__ void gload_lds16(const void* g, void* l) {
    __builtin_amdgcn_global_load_lds(
        (const __attribute__((address_space(1))) uint32_t*)g,
        (__attribute__((address_space(3))) uint32_t*)l, 16, 0, 0);
}

// ---------------------------------------------------------------------------
// prep: blocks [0,32):  tau table pairs tab2[n][e] = (f_n(s_e), f_n(s_{e+1}))
//                       n = bid*4+(tid>>6), e = tid&63, NE=64 over [-8,8]
//       blocks [32,80): W1,W2 -> bf16 in MFMA fragment order
// fragment order (k-slice kk of 32, chunk c in [0,1024)): nf=c>>6, ll=c&63,
//   col = nf*16 + (ll&15), k = kk*32 + (ll>>4)*8 + i   (i = 0..7)
// ---------------------------------------------------------------------------
__global__ void prep(const float* __restrict__ w1, const float* __restrict__ w2,
                     const float* __restrict__ wt1, const float* __restrict__ bt1,
                     const float* __restrict__ wt2, const float* __restrict__ bt2,
                     float2* __restrict__ tab2,
                     bf16x8* __restrict__ w1f, bf16x8* __restrict__ w2f) {
    const int bid = blockIdx.x, tid = threadIdx.x;
    if (bid < 32) {
        const int n = bid * 4 + (tid >> 6);
        const int e = tid & 63;
        float s = SMIN + (SMAX - SMIN) * (float)e / (float)(NE - 1);
        float acc = bt2[n];
        for (int h = 0; h < HTAU; ++h) {
            float z  = s * wt1[n * HTAU + h] + bt1[n * HTAU + h];
            float sp = (z > 20.f) ? z : log1pf(expf(z));
            acc += wt2[n * HTAU + h] * sp;
        }
        float nxt = __shfl_down(acc, 1, 64);          // e==63 never interpolated
        tab2[n * NE + e] = make_float2(acc, nxt);
    } else {
        const int cid  = (bid - 32) * 256 + tid;      // 0..12287
        const int isW2 = cid >= 4096;
        const int c2   = isW2 ? cid - 4096 : cid;
        const int kk = c2 >> 10, c = c2 & 1023;
        const int nf = c >> 6,  ll = c & 63;
        const int col = nf * 16 + (ll & 15);
        const int kr  = kk * 32 + (ll >> 4) * 8;
        const float* src = isW2 ? (w2 + col * H1_ + kr) : (w1 + col * D_IN + kr);
        float tmp[8];
        *(f32x4*)tmp       = *(const f32x4*)src;
        *(f32x4*)(tmp + 4) = *(const f32x4*)(src + 4);
        (isW2 ? w2f : w1f)[c2] = cvt8(tmp);
    }
}

// ---------------------------------------------------------------------------
// fused_main: mu branch (MFMA) + tau/out_lr branch, one pass over x.
// BM=64 rows/wg, 256 threads (4 waves), grid 512, 2 wgs/CU.
// K-step = 64 (two 32-K slices staged together): 32 MFMA per barrier pair,
// only 6 stage->drain events total (was 12 in r4). Single wsl buffer,
// r4's proven sync->MFMA->sync->issue ordering (no dbuf: r5 showed the
// compiler drains vmcnt(0) before MFMA when stage precedes it).
// LDS = 32KB wsl + 32KB h1 (swizzled bf16) = 64.5KB -> 2 wgs/CU.
// ---------------------------------------------------------------------------
__global__ __launch_bounds__(256, 2)
void fused_main(const float* __restrict__ x,
                const bf16x8* __restrict__ w1f, const bf16x8* __restrict__ w2f,
                const float* __restrict__ b1, const float* __restrict__ b2,
                const float* __restrict__ w3, const float* __restrict__ b3,
                const float2* __restrict__ tab2, const float* __restrict__ wlr,
                const float* __restrict__ blr,
                float* __restrict__ mu_out, float* __restrict__ lr_out) {
    __shared__ bf16x8 wsl[2048];         // 32KB: one 64-K W slice (frag order)
    __shared__ char   h1_raw[64 * 512];  // 32KB bf16 [64][256], swizzled

    const int tid = threadIdx.x;
    const int l   = tid & 63;
    const int w   = tid >> 6;            // wave 0..3
    const int q   = l >> 4;
    const int l15 = l & 15;
    const int row = w * 16 + l15;        // block-local row 0..63
    const int rb  = blockIdx.x * 64;

    // ---- prologue: stage W1 K-step 0 (chunks 0..2047); x + w_lr to regs ----
#pragma unroll
    for (int j = 0; j < 8; ++j)
        gload_lds16(w1f + w * 512 + j * 64 + l, &wsl[w * 512 + j * 64]);

    float xv[32], wlv[32];
    {
        const float* xr = x + (size_t)(rb + row) * D_IN;
#pragma unroll
        for (int kk = 0; kk < 4; ++kk) {
            *(f32x4*)(xv + kk * 8)      = *(const f32x4*)(xr + kk * 32 + q * 8);
            *(f32x4*)(xv + kk * 8 + 4)  = *(const f32x4*)(xr + kk * 32 + q * 8 + 4);
            *(f32x4*)(wlv + kk * 8)     = *(const f32x4*)(wlr + kk * 32 + q * 8);
            *(f32x4*)(wlv + kk * 8 + 4) = *(const f32x4*)(wlr + kk * 32 + q * 8 + 4);
        }
    }
    bf16x8 a1[4];
#pragma unroll
    for (int kk = 0; kk < 4; ++kk) a1[kk] = cvt8(xv + kk * 8);

    // ---- tau branch (L2 gathers overlap the W1 staging drain) ----
    {
        const float INVDS = (float)(NE - 1) / (SMAX - SMIN);
        float tsum = 0.f;
#pragma unroll
        for (int kk = 0; kk < 4; ++kk) {
#pragma unroll
            for (int i = 0; i < 8; ++i) {
                float s = xv[kk * 8 + i];
                s = fminf(fmaxf(s, SMIN), SMAX);
                float u = (s - SMIN) * INVDS;
                int ii = (int)u;
                ii = ii > NE - 2 ? NE - 2 : ii;
                float fr = u - (float)ii;
                int n = kk * 32 + q * 8 + i;
                float2 tv = tab2[n * NE + ii];
                tsum += wlv[kk * 8 + i] * (tv.x + (tv.y - tv.x) * fr);
            }
        }
        tsum += __shfl_xor(tsum, 16, 64);
        tsum += __shfl_xor(tsum, 32, 64);
        if (q == 0) lr_out[rb + row] = tsum + blr[0];
    }

    f32x4 acc[16];
#pragma unroll
    for (int f = 0; f < 16; ++f) acc[f] = (f32x4){0.f, 0.f, 0.f, 0.f};

    // ---- mu layer 1 (K = 128, 2 K-steps of 64) ----
#pragma unroll
    for (int s = 0; s < 2; ++s) {
        __syncthreads();                  // staged slice resident
#pragma unroll
        for (int kh = 0; kh < 2; ++kh)
#pragma unroll
            for (int nf = 0; nf < 16; ++nf)
                acc[nf] = __builtin_amdgcn_mfma_f32_16x16x32_bf16(
                    a1[s * 2 + kh], wsl[kh * 1024 + nf * 64 + l], acc[nf], 0, 0, 0);

        if (s == 1) {  // epilogue 1: h1 = relu(acc+b1) -> LDS, swizzled
#pragma unroll
            for (int f = 0; f < 16; ++f) {
                int col = f * 16 + l15;
                float bias = b1[col];
#pragma unroll
                for (int r = 0; r < 4; ++r) {
                    int gr = w * 16 + q * 4 + r;
                    float v = acc[f][r] + bias;
                    v = v > 0.f ? v : 0.f;
                    int byte = (gr * 512 + col * 2) ^ ((gr & 7) << 4);
                    *(bf16_t*)(h1_raw + byte) = (bf16_t)v;
                }
                acc[f] = (f32x4){0.f, 0.f, 0.f, 0.f};
            }
        }
        __syncthreads();                  // all waves done reading wsl
        const bf16x8* nsrc = (s == 0) ? (w1f + 2048) : w2f;
#pragma unroll
        for (int j = 0; j < 8; ++j)
            gload_lds16(nsrc + w * 512 + j * 64 + l, &wsl[w * 512 + j * 64]);
    }

    // ---- mu layer 2 (K = 256, 4 K-steps of 64) ----
#pragma unroll
    for (int s = 0; s < 4; ++s) {
        __syncthreads();                  // staged slice resident
#pragma unroll
        for (int kh = 0; kh < 2; ++kh) {
            int k0   = (s * 2 + kh) * 32 + q * 8;
            int byte = (row * 512 + k0 * 2) ^ ((row & 7) << 4);
            bf16x8 a = *(bf16x8*)(h1_raw + byte);
#pragma unroll
            for (int nf = 0; nf < 16; ++nf)
                acc[nf] = __builtin_amdgcn_mfma_f32_16x16x32_bf16(
                    a, wsl[kh * 1024 + nf * 64 + l], acc[nf], 0, 0, 0);
        }
        if (s < 3) {
            __syncthreads();
#pragma unroll
            for (int j = 0; j < 8; ++j)
                gload_lds16(w2f + (s + 1) * 2048 + w * 512 + j * 64 + l,
                            &wsl[w * 512 + j * 64]);
        }
    }

    // ---- epilogue 2: mu = relu(acc + b2) . w3 + b3 ----
    float p[4] = {0.f, 0.f, 0.f, 0.f};
#pragma unroll
    for (int f = 0; f < 16; ++f) {
        int col = f * 16 + l15;
        float bias = b2[col];
        float wv   = w3[col];
#pragma unroll
        for (int r = 0; r < 4; ++r) {
            float v = acc[f][r] + bias;
            v = v > 0.f ? v : 0.f;
            p[r] += v * wv;
        }
    }
#pragma unroll
    for (int m = 1; m < 16; m <<= 1) {
#pragma unroll
        for (int r = 0; r < 4; ++r) p[r] += __shfl_xor(p[r], m, 64);
    }
    if (l15 == 0) {
        float bb = b3[0];
#pragma unroll
        for (int r = 0; r < 4; ++r)
            mu_out[rb + w * 16 + q * 4 + r] = p[r] + bb;
    }
}

extern "C" void kernel_launch(void* const* d_in, const int* in_sizes, int n_in,
                              void* d_out, int out_size, void* d_ws, size_t ws_size,
                              hipStream_t stream) {
    const float* x   = (const float*)d_in[0];
    const float* w1  = (const float*)d_in[1];
    const float* b1  = (const float*)d_in[2];
    const float* w2  = (const float*)d_in[3];
    const float* b2  = (const float*)d_in[4];
    const float* w3  = (const float*)d_in[5];
    const float* b3  = (const float*)d_in[6];
    const float* wt1 = (const float*)d_in[7];
    const float* bt1 = (const float*)d_in[8];
    const float* wt2 = (const float*)d_in[9];
    const float* bt2 = (const float*)d_in[10];
    const float* wlr = (const float*)d_in[11];
    const float* blr = (const float*)d_in[12];

    float* out    = (float*)d_out;
    float* mu_out = out;                 // output 0: mu     [32768]
    float* lr_out = out + B_ROWS;        // output 1: out_lr [32768]

    char* ws = (char*)d_ws;
    float2* tab2 = (float2*)ws;                   // 64KB  (128*64 float2)
    bf16x8* w1f  = (bf16x8*)(ws + (64 << 10));    // 64KB  (4096 chunks)
    bf16x8* w2f  = (bf16x8*)(ws + (128 << 10));   // 128KB (8192 chunks)

    prep<<<80, 256, 0, stream>>>(w1, w2, wt1, bt1, wt2, bt2, tab2, w1f, w2f);
    fused_main<<<B_ROWS / 64, 256, 0, stream>>>(x, w1f, w2f, b1, b2, w3, b3,
                                                tab2, wlr, blr, mu_out, lr_out);
}

// Round 7
// 33.155 us; speedup vs baseline: 1.1549x; 1.0355x over previous
//
#include <hip/hip_runtime.h>
#include <hip/hip_bf16.h>

#define B_ROWS 32768
#define D_IN   128
#define H1_    256
#define HTAU   32
#define NBLK   128

#define NE     64
#define SMIN  (-8.0f)
#define SMAX  ( 8.0f)

typedef __bf16 bf16_t;
typedef bf16_t bf16x8 __attribute__((ext_vector_type(8)));
typedef float  f32x4  __attribute__((ext_vector_type(4)));

__device__ __forceinline__ bf16x8 cvt8(const float* v) {
    bf16x8 r;
#pragma unroll
    for (int i = 0; i < 8; ++i) r[i] = (bf16_t)v[i];
    return r;
}

// async global->LDS, 16B/lane; LDS dest = wave-uniform base + lane*16
__device__ __forceinline__ void gload_lds16(const void* g, void* l) {
    __builtin_amdgcn_global_load_lds(
        (const __attribute__((address_space(1))) uint32_t*)g,
        (__attribute__((address_space(3))) uint32_t*)l, 16, 0, 0);
}

// ---------------------------------------------------------------------------
// prep: blocks [0,128):  tau table pairs tab2[n][e] = (f_n(s_e), f_n(s_{e+1}))
//   n = bid; 4 waves split the h-sum (8 each, ~4x shorter serial transc chain),
//   LDS reduce, wave 0 pairs via shfl_down and stores.
//       blocks [128,176): W1,W2 -> bf16 in MFMA fragment order
// fragment order (k-slice kk of 32, chunk c in [0,1024)): nf=c>>6, ll=c&63,
//   col = nf*16 + (ll&15), k = kk*32 + (ll>>4)*8 + i   (i = 0..7)
// ---------------------------------------------------------------------------
__global__ void prep(const float* __restrict__ w1, const float* __restrict__ w2,
                     const float* __restrict__ wt1, const float* __restrict__ bt1,
                     const float* __restrict__ wt2, const float* __restrict__ bt2,
                     float2* __restrict__ tab2,
                     bf16x8* __restrict__ w1f, bf16x8* __restrict__ w2f) {
    __shared__ float ps[4][64];
    const int bid = blockIdx.x, tid = threadIdx.x;
    if (bid < NBLK) {
        const int n  = bid;
        const int e  = tid & 63;
        const int hh = tid >> 6;                  // wave 0..3 -> 8-h slice
        float s = SMIN + (SMAX - SMIN) * (float)e / (float)(NE - 1);
        float part = (hh == 0) ? bt2[n] : 0.f;
#pragma unroll
        for (int j = 0; j < 8; ++j) {
            int h = hh * 8 + j;
            float z  = s * wt1[n * HTAU + h] + bt1[n * HTAU + h];
            float sp = (z > 20.f) ? z : log1pf(expf(z));
            part += wt2[n * HTAU + h] * sp;
        }
        ps[hh][e] = part;
        __syncthreads();
        if (hh == 0) {
            float acc = ps[0][e] + ps[1][e] + ps[2][e] + ps[3][e];
            float nxt = __shfl_down(acc, 1, 64);  // e==63 never interpolated
            tab2[n * NE + e] = make_float2(acc, nxt);
        }
    } else {
        const int cid  = (bid - NBLK) * 256 + tid;    // 0..12287
        const int isW2 = cid >= 4096;
        const int c2   = isW2 ? cid - 4096 : cid;
        const int kk = c2 >> 10, c = c2 & 1023;
        const int nf = c >> 6,  ll = c & 63;
        const int col = nf * 16 + (ll & 15);
        const int kr  = kk * 32 + (ll >> 4) * 8;
        const float* src = isW2 ? (w2 + col * H1_ + kr) : (w1 + col * D_IN + kr);
        float tmp[8];
        *(f32x4*)tmp       = *(const f32x4*)src;
        *(f32x4*)(tmp + 4) = *(const f32x4*)(src + 4);
        (isW2 ? w2f : w1f)[c2] = cvt8(tmp);
    }
}

// ---------------------------------------------------------------------------
// fused_main: mu branch (MFMA) + tau/out_lr branch, one pass over x.
// BM=64 rows/wg, 256 threads (4 waves), grid 512, 2 wgs/CU.
// K-step = 64 (two 32-K slices staged together): 32 MFMA per barrier pair,
// 6 stage->drain events. Single wsl buffer (r5 showed dbuf regresses:
// compiler drains vmcnt(0) before MFMA when stage precedes it).
// r7: x-loads issued first (longest pole); tau lerp in prologue but lr_out
// store deferred to the barrier-free kernel tail (store-ack out of barrier 1).
// LDS = 32KB wsl + 32KB h1 (swizzled bf16) = 64.5KB -> 2 wgs/CU.
// ---------------------------------------------------------------------------
__global__ __launch_bounds__(256, 2)
void fused_main(const float* __restrict__ x,
                const bf16x8* __restrict__ w1f, const bf16x8* __restrict__ w2f,
                const float* __restrict__ b1, const float* __restrict__ b2,
                const float* __restrict__ w3, const float* __restrict__ b3,
                const float2* __restrict__ tab2, const float* __restrict__ wlr,
                const float* __restrict__ blr,
                float* __restrict__ mu_out, float* __restrict__ lr_out) {
    __shared__ bf16x8 wsl[2048];         // 32KB: one 64-K W slice (frag order)
    __shared__ char   h1_raw[64 * 512];  // 32KB bf16 [64][256], swizzled

    const int tid = threadIdx.x;
    const int l   = tid & 63;
    const int w   = tid >> 6;            // wave 0..3
    const int q   = l >> 4;
    const int l15 = l & 15;
    const int row = w * 16 + l15;        // block-local row 0..63
    const int rb  = blockIdx.x * 64;

    // ---- prologue: x loads FIRST (HBM, longest pole) ----
    float xv[32], wlv[32];
    {
        const float* xr = x + (size_t)(rb + row) * D_IN;
#pragma unroll
        for (int kk = 0; kk < 4; ++kk) {
            *(f32x4*)(xv + kk * 8)     = *(const f32x4*)(xr + kk * 32 + q * 8);
            *(f32x4*)(xv + kk * 8 + 4) = *(const f32x4*)(xr + kk * 32 + q * 8 + 4);
        }
    }
    // stage W1 K-step 0 (chunks 0..2047)
#pragma unroll
    for (int j = 0; j < 8; ++j)
        gload_lds16(w1f + w * 512 + j * 64 + l, &wsl[w * 512 + j * 64]);
    // w_lr to regs (L2 broadcast)
#pragma unroll
    for (int kk = 0; kk < 4; ++kk) {
        *(f32x4*)(wlv + kk * 8)     = *(const f32x4*)(wlr + kk * 32 + q * 8);
        *(f32x4*)(wlv + kk * 8 + 4) = *(const f32x4*)(wlr + kk * 32 + q * 8 + 4);
    }
    bf16x8 a1[4];
#pragma unroll
    for (int kk = 0; kk < 4; ++kk) a1[kk] = cvt8(xv + kk * 8);

    // ---- tau branch: compute tsum now (gathers overlap W1 staging drain);
    //      store deferred to the barrier-free kernel tail ----
    float tsum = 0.f;
    {
        const float INVDS = (float)(NE - 1) / (SMAX - SMIN);
#pragma unroll
        for (int kk = 0; kk < 4; ++kk) {
#pragma unroll
            for (int i = 0; i < 8; ++i) {
                float s = xv[kk * 8 + i];
                s = fminf(fmaxf(s, SMIN), SMAX);
                float u = (s - SMIN) * INVDS;
                int ii = (int)u;
                ii = ii > NE - 2 ? NE - 2 : ii;
                float fr = u - (float)ii;
                int n = kk * 32 + q * 8 + i;
                float2 tv = tab2[n * NE + ii];
                tsum += wlv[kk * 8 + i] * (tv.x + (tv.y - tv.x) * fr);
            }
        }
        tsum += __shfl_xor(tsum, 16, 64);
        tsum += __shfl_xor(tsum, 32, 64);
    }

    f32x4 acc[16];
#pragma unroll
    for (int f = 0; f < 16; ++f) acc[f] = (f32x4){0.f, 0.f, 0.f, 0.f};

    // ---- mu layer 1 (K = 128, 2 K-steps of 64) ----
#pragma unroll
    for (int s = 0; s < 2; ++s) {
        __syncthreads();                  // staged slice resident
#pragma unroll
        for (int kh = 0; kh < 2; ++kh)
#pragma unroll
            for (int nf = 0; nf < 16; ++nf)
                acc[nf] = __builtin_amdgcn_mfma_f32_16x16x32_bf16(
                    a1[s * 2 + kh], wsl[kh * 1024 + nf * 64 + l], acc[nf], 0, 0, 0);

        if (s == 1) {  // epilogue 1: h1 = relu(acc+b1) -> LDS, swizzled
#pragma unroll
            for (int f = 0; f < 16; ++f) {
                int col = f * 16 + l15;
                float bias = b1[col];
#pragma unroll
                for (int r = 0; r < 4; ++r) {
                    int gr = w * 16 + q * 4 + r;
                    float v = acc[f][r] + bias;
                    v = v > 0.f ? v : 0.f;
                    int byte = (gr * 512 + col * 2) ^ ((gr & 7) << 4);
                    *(bf16_t*)(h1_raw + byte) = (bf16_t)v;
                }
                acc[f] = (f32x4){0.f, 0.f, 0.f, 0.f};
            }
        }
        __syncthreads();                  // all waves done reading wsl
        const bf16x8* nsrc = (s == 0) ? (w1f + 2048) : w2f;
#pragma unroll
        for (int j = 0; j < 8; ++j)
            gload_lds16(nsrc + w * 512 + j * 64 + l, &wsl[w * 512 + j * 64]);
    }

    // ---- mu layer 2 (K = 256, 4 K-steps of 64) ----
#pragma unroll
    for (int s = 0; s < 4; ++s) {
        __syncthreads();                  // staged slice resident
#pragma unroll
        for (int kh = 0; kh < 2; ++kh) {
            int k0   = (s * 2 + kh) * 32 + q * 8;
            int byte = (row * 512 + k0 * 2) ^ ((row & 7) << 4);
            bf16x8 a = *(bf16x8*)(h1_raw + byte);
#pragma unroll
            for (int nf = 0; nf < 16; ++nf)
                acc[nf] = __builtin_amdgcn_mfma_f32_16x16x32_bf16(
                    a, wsl[kh * 1024 + nf * 64 + l], acc[nf], 0, 0, 0);
        }
        if (s < 3) {
            __syncthreads();
#pragma unroll
            for (int j = 0; j < 8; ++j)
                gload_lds16(w2f + (s + 1) * 2048 + w * 512 + j * 64 + l,
                            &wsl[w * 512 + j * 64]);
        }
    }

    // ---- epilogue 2: mu = relu(acc + b2) . w3 + b3 ----
    float p[4] = {0.f, 0.f, 0.f, 0.f};
#pragma unroll
    for (int f = 0; f < 16; ++f) {
        int col = f * 16 + l15;
        float bias = b2[col];
        float wv   = w3[col];
#pragma unroll
        for (int r = 0; r < 4; ++r) {
            float v = acc[f][r] + bias;
            v = v > 0.f ? v : 0.f;
            p[r] += v * wv;
        }
    }
#pragma unroll
    for (int m = 1; m < 16; m <<= 1) {
#pragma unroll
        for (int r = 0; r < 4; ++r) p[r] += __shfl_xor(p[r], m, 64);
    }
    if (l15 == 0) {
        float bb = b3[0];
#pragma unroll
        for (int r = 0; r < 4; ++r)
            mu_out[rb + w * 16 + q * 4 + r] = p[r] + bb;
    }
    // deferred tau store (barrier-free tail)
    if (q == 0) lr_out[rb + row] = tsum + blr[0];
}

extern "C" void kernel_launch(void* const* d_in, const int* in_sizes, int n_in,
                              void* d_out, int out_size, void* d_ws, size_t ws_size,
                              hipStream_t stream) {
    const float* x   = (const float*)d_in[0];
    const float* w1  = (const float*)d_in[1];
    const float* b1  = (const float*)d_in[2];
    const float* w2  = (const float*)d_in[3];
    const float* b2  = (const float*)d_in[4];
    const float* w3  = (const float*)d_in[5];
    const float* b3  = (const float*)d_in[6];
    const float* wt1 = (const float*)d_in[7];
    const float* bt1 = (const float*)d_in[8];
    const float* wt2 = (const float*)d_in[9];
    const float* bt2 = (const float*)d_in[10];
    const float* wlr = (const float*)d_in[11];
    const float* blr = (const float*)d_in[12];

    float* out    = (float*)d_out;
    float* mu_out = out;                 // output 0: mu     [32768]
    float* lr_out = out + B_ROWS;        // output 1: out_lr [32768]

    char* ws = (char*)d_ws;
    float2* tab2 = (float2*)ws;                   // 64KB  (128*64 float2)
    bf16x8* w1f  = (bf16x8*)(ws + (64 << 10));    // 64KB  (4096 chunks)
    bf16x8* w2f  = (bf16x8*)(ws + (128 << 10));   // 128KB (8192 chunks)

    prep<<<NBLK + 48, 256, 0, stream>>>(w1, w2, wt1, bt1, wt2, bt2, tab2, w1f, w2f);
    fused_main<<<B_ROWS / 64, 256, 0, stream>>>(x, w1f, w2f, b1, b2, w3, b3,
                                                tab2, wlr, blr, mu_out, lr_out);
}